// Round 1
// baseline (276.857 us; speedup 1.0000x reference)
//
#include <hip/hip_runtime.h>

#define IMG 192

// ---------------- Pass 1 (x-direction), all 5 channels fused ----------------
// B1 layout: [5][z][y][ox], channel stride n1 = 192*192*O
__global__ void pass1_all(const float* __restrict__ I, const float* __restrict__ T,
                          float* __restrict__ B1, int O, int s, int k, int n1) {
    int idx = blockIdx.x * blockDim.x + threadIdx.x;
    int total = IMG * IMG * O;
    if (idx >= total) return;
    int ox = idx % O;
    int zy = idx / O;                 // z*192 + y
    const float* pI = I + (size_t)zy * IMG + ox * s;
    const float* pT = T + (size_t)zy * IMG + ox * s;
    float sI = 0.f, sT = 0.f, sI2 = 0.f, sT2 = 0.f, sIT = 0.f;
    for (int i = 0; i < k; ++i) {
        float a = pI[2 * i];
        float b = pT[2 * i];
        sI += a; sT += b; sI2 += a * a; sT2 += b * b; sIT += a * b;
    }
    B1[0 * n1 + idx] = sI;
    B1[1 * n1 + idx] = sT;
    B1[2 * n1 + idx] = sI2;
    B1[3 * n1 + idx] = sT2;
    B1[4 * n1 + idx] = sIT;
}

// ---------------- Pass 1 single-channel fallback ----------------
__global__ void pass1_one(const float* __restrict__ I, const float* __restrict__ T,
                          float* __restrict__ B1, int O, int s, int k, int c) {
    int idx = blockIdx.x * blockDim.x + threadIdx.x;
    int total = IMG * IMG * O;
    if (idx >= total) return;
    int ox = idx % O;
    int zy = idx / O;
    const float* pI = I + (size_t)zy * IMG + ox * s;
    const float* pT = T + (size_t)zy * IMG + ox * s;
    float acc = 0.f;
    for (int i = 0; i < k; ++i) {
        float v;
        if (c == 0)      v = pI[2 * i];
        else if (c == 1) v = pT[2 * i];
        else if (c == 2) { float a = pI[2 * i]; v = a * a; }
        else if (c == 3) { float b = pT[2 * i]; v = b * b; }
        else             { v = pI[2 * i] * pT[2 * i]; }
        acc += v;
    }
    B1[idx] = acc;
}

// ---------------- Pass 2 (y-direction) ----------------
// Bin  [nch][z=192][y=192][ox=O]  (n1 per channel)
// Bout [nch][z=192][oy=O][ox=O]   (n2 per channel)
__global__ void pass_y(const float* __restrict__ Bin, float* __restrict__ Bout,
                       int O, int s, int k, int nch, int n1, int n2) {
    int idx = blockIdx.x * blockDim.x + threadIdx.x;
    int total = nch * n2;
    if (idx >= total) return;
    int c = idx / n2;
    int r = idx - c * n2;
    int ox = r % O;
    int t  = r / O;
    int oy = t % O;
    int z  = t / O;
    const float* p = Bin + (size_t)c * n1 + (size_t)z * IMG * O + (size_t)(oy * s) * O + ox;
    float acc = 0.f;
    int stride = 2 * O;
    for (int j = 0; j < k; ++j) acc += p[(size_t)j * stride];
    Bout[idx] = acc;
}

// ---------------- Pass 3 (z-direction) ----------------
// Bin  [nch][z=192][oy=O][ox=O]  (n2 per channel)
// Bout [coff + c][n3]            (n3 = O^3 per channel, 5-channel B3 buffer)
__global__ void pass_z(const float* __restrict__ Bin, float* __restrict__ Bout,
                       int O, int s, int k, int nch, int coff, int n2, int n3) {
    int idx = blockIdx.x * blockDim.x + threadIdx.x;
    int total = nch * n3;
    if (idx >= total) return;
    int c = idx / n3;
    int r = idx - c * n3;
    int ox = r % O;
    int t  = r / O;
    int oy = t % O;
    int oz = t / O;
    const float* p = Bin + (size_t)c * n2 + (size_t)(oz * s) * O * O + (size_t)oy * O + ox;
    float acc = 0.f;
    int stride = 2 * O * O;
    for (int l = 0; l < k; ++l) acc += p[(size_t)l * stride];
    Bout[(size_t)(coff + c) * n3 + r] = acc;
}

// ---------------- LNCC reduce: per-block partial sums ----------------
__global__ void reduce_lncc(const float* __restrict__ B3, int n3, float inv_numel,
                            float* __restrict__ partials) {
    float local = 0.f;
    for (int i = blockIdx.x * blockDim.x + threadIdx.x; i < n3;
         i += gridDim.x * blockDim.x) {
        float i_s = B3[i];
        float t_s = B3[(size_t)n3 + i];
        float i2  = B3[2 * (size_t)n3 + i];
        float t2  = B3[3 * (size_t)n3 + i];
        float it  = B3[4 * (size_t)n3 + i];
        float cross = it - i_s * t_s * inv_numel;
        float ivar  = i2 - i_s * i_s * inv_numel;
        float tvar  = t2 - t_s * t_s * inv_numel;
        float lncc  = cross * cross / (ivar * tvar + 1e-5f);
        local += lncc;
    }
    __shared__ float red[256];
    red[threadIdx.x] = local;
    __syncthreads();
    for (int off = 128; off > 0; off >>= 1) {
        if (threadIdx.x < off) red[threadIdx.x] += red[threadIdx.x + off];
        __syncthreads();
    }
    if (threadIdx.x == 0) partials[blockIdx.x] = red[0];
}

// ---------------- finalize: out += w * (1 - mean) ----------------
__global__ void finalize(const float* __restrict__ partials, int nblk,
                         float* __restrict__ out, float w, float inv_n) {
    __shared__ float red[256];
    float v = (threadIdx.x < nblk) ? partials[threadIdx.x] : 0.f;
    red[threadIdx.x] = v;
    __syncthreads();
    for (int off = 128; off > 0; off >>= 1) {
        if (threadIdx.x < off) red[threadIdx.x] += red[threadIdx.x + off];
        __syncthreads();
    }
    if (threadIdx.x == 0) out[0] += w * (1.0f - red[0] * inv_n);
}

extern "C" void kernel_launch(void* const* d_in, const int* in_sizes, int n_in,
                              void* d_out, int out_size, void* d_ws, size_t ws_size,
                              hipStream_t stream) {
    const float* I = (const float*)d_in[0];
    const float* T = (const float*)d_in[1];
    float* out = (float*)d_out;
    float* ws  = (float*)d_ws;

    hipMemsetAsync(d_out, 0, sizeof(float), stream);

    const int   Ks[3] = {12, 24, 48};
    const float Wt[3] = {0.1f, 0.3f, 0.6f};
    const int   Ss[3] = {3, 6, 12};
    const int   Os[3] = {57, 25, 9};

    const size_t n1max = (size_t)IMG * IMG * 57;   // 2,101,248
    const size_t n2max = (size_t)IMG * 57 * 57;    //   623,808
    const size_t n3max = (size_t)57 * 57 * 57;     //   185,193

    size_t needAll = (5 * (n1max + n2max + n3max) + 512) * sizeof(float);
    bool allmode = (ws_size >= needAll);

    float* B1 = ws;
    float* B2;
    float* B3;
    float* partials;
    if (allmode) {
        B2 = B1 + 5 * n1max;
        B3 = B2 + 5 * n2max;
        partials = B3 + 5 * n3max;
    } else {
        B2 = B1 + n1max;
        B3 = B2 + n2max;
        partials = B3 + 5 * n3max;
    }

    for (int sc = 0; sc < 3; ++sc) {
        int k = Ks[sc], s = Ss[sc], O = Os[sc];
        int n1 = IMG * IMG * O;
        int n2 = IMG * O * O;
        int n3 = O * O * O;

        if (allmode) {
            int tot1 = IMG * IMG * O;
            pass1_all<<<(tot1 + 255) / 256, 256, 0, stream>>>(I, T, B1, O, s, k, n1);
            int tot2 = 5 * n2;
            pass_y<<<(tot2 + 255) / 256, 256, 0, stream>>>(B1, B2, O, s, k, 5, n1, n2);
            int tot3 = 5 * n3;
            pass_z<<<(tot3 + 255) / 256, 256, 0, stream>>>(B2, B3, O, s, k, 5, 0, n2, n3);
        } else {
            for (int c = 0; c < 5; ++c) {
                int tot1 = IMG * IMG * O;
                pass1_one<<<(tot1 + 255) / 256, 256, 0, stream>>>(I, T, B1, O, s, k, c);
                pass_y<<<(n2 + 255) / 256, 256, 0, stream>>>(B1, B2, O, s, k, 1, n1, n2);
                pass_z<<<(n3 + 255) / 256, 256, 0, stream>>>(B2, B3, O, s, k, 1, c, n2, n3);
            }
        }

        int nblk = (n3 + 255) / 256;
        if (nblk > 256) nblk = 256;
        reduce_lncc<<<nblk, 256, 0, stream>>>(B3, n3, 1.0f / ((float)k * k * k), partials);
        finalize<<<1, 256, 0, stream>>>(partials, nblk, out, Wt[sc], 1.0f / (float)n3);
    }
}

// Round 2
// 119.938 us; speedup vs baseline: 2.3083x; 2.3083x over previous
//
#include <hip/hip_runtime.h>

#define IMG 192

// ---------------------------------------------------------------------------
// Pass 1 (x-direction): LDS-staged, coalesced, all 5 channels, up to 3 scales
// fused. Each block stages 8 contiguous rows (8*192 floats) of I and T.
// B layout per scale: [5][zy][ox], channel stride n1 = 36864*O.
// Null scale pointer => that scale skipped.
// ---------------------------------------------------------------------------
__global__ __launch_bounds__(256) void pass1_lds(
    const float* __restrict__ I, const float* __restrict__ T,
    float* __restrict__ Bs0, float* __restrict__ Bs1, float* __restrict__ Bs2)
{
    __shared__ float lI[8 * IMG];
    __shared__ float lT[8 * IMG];
    const int tid = threadIdx.x;
    const int r0  = blockIdx.x * 8;                 // first row (zy index)

    const float4* I4 = (const float4*)(I + (size_t)r0 * IMG);
    const float4* T4 = (const float4*)(T + (size_t)r0 * IMG);
    float4* lI4 = (float4*)lI;
    float4* lT4 = (float4*)lT;
    for (int t = tid; t < (8 * IMG) / 4; t += 256) {   // 384 float4
        lI4[t] = I4[t];
        lT4[t] = T4[t];
    }
    __syncthreads();

    const int t0 = Bs0 ? 57 : 0;
    const int t1 = t0 + (Bs1 ? 25 : 0);
    const int Pt = t1 + (Bs2 ? 9 : 0);
    const int nitems = 8 * Pt;

    for (int w = tid; w < nitems; w += 256) {
        int row = w / Pt;
        int p   = w - row * Pt;
        float* B; int ox, O, s, k, n1;
        if (p < t0)      { B = Bs0; ox = p;      O = 57; s = 3;  k = 12; n1 = 2101248; }
        else if (p < t1) { B = Bs1; ox = p - t0; O = 25; s = 6;  k = 24; n1 = 921600;  }
        else             { B = Bs2; ox = p - t1; O = 9;  s = 12; k = 48; n1 = 331776;  }

        const float* a = &lI[row * IMG + ox * s];
        const float* b = &lT[row * IMG + ox * s];
        float sI = 0.f, sT = 0.f, sI2 = 0.f, sT2 = 0.f, sIT = 0.f;
        for (int i = 0; i < k; ++i) {
            float x = a[2 * i];
            float y = b[2 * i];
            sI += x; sT += y; sI2 += x * x; sT2 += y * y; sIT += x * y;
        }
        size_t o = (size_t)(r0 + row) * O + ox;
        B[o]                    = sI;
        B[(size_t)n1 + o]       = sT;
        B[2 * (size_t)n1 + o]   = sI2;
        B[3 * (size_t)n1 + o]   = sT2;
        B[4 * (size_t)n1 + o]   = sIT;
    }
}

// ---------------------------------------------------------------------------
// Pass 2 (y-direction), all 3 scales in one launch via block ranges.
// B1 region: scale offsets {0, 10506240, 15114240} (floats).
// B2 region: scale offsets {0,  3119040,  3719040}.
// ---------------------------------------------------------------------------
__global__ __launch_bounds__(256) void passY_all(
    const float* __restrict__ B1, float* __restrict__ B2)
{
    const int b = blockIdx.x;
    int sc, bloc;
    if (b < 12184)      { sc = 0; bloc = b; }
    else if (b < 14528) { sc = 1; bloc = b - 12184; }
    else                { sc = 2; bloc = b - 14528; }

    const int    Os[3]  = {57, 25, 9};
    const int    Ss[3]  = {3, 6, 12};
    const int    Ks[3]  = {12, 24, 48};
    const int    N1[3]  = {2101248, 921600, 331776};
    const int    N2[3]  = {623808, 120000, 15552};
    const size_t OF1[3] = {0, 10506240, 15114240};
    const size_t OF2[3] = {0, 3119040, 3719040};

    const int O = Os[sc], s = Ss[sc], k = Ks[sc], n1 = N1[sc], n2 = N2[sc];
    int idx = bloc * 256 + threadIdx.x;
    if (idx >= 5 * n2) return;
    int c  = idx / n2;
    int r  = idx - c * n2;
    int ox = r % O;
    int t  = r / O;
    int oy = t % O;
    int z  = t / O;

    const float* p = B1 + OF1[sc] + (size_t)c * n1
                     + (size_t)z * IMG * O + (size_t)(oy * s) * O + ox;
    float acc = 0.f;
    const int stride = 2 * O;
    for (int j = 0; j < k; ++j) acc += p[(size_t)j * stride];
    B2[OF2[sc] + idx] = acc;
}

// ---------------------------------------------------------------------------
// Pass 3 (z-direction), all 3 scales in one launch.
// B3 region: scale offsets {0, 925965, 1004090} (floats), [5][n3] per scale.
// ---------------------------------------------------------------------------
__global__ __launch_bounds__(256) void passZ_all(
    const float* __restrict__ B2, float* __restrict__ B3)
{
    const int b = blockIdx.x;
    int sc, bloc;
    if (b < 3618)      { sc = 0; bloc = b; }
    else if (b < 3924) { sc = 1; bloc = b - 3618; }
    else               { sc = 2; bloc = b - 3924; }

    const int    Os[3]  = {57, 25, 9};
    const int    Ss[3]  = {3, 6, 12};
    const int    Ks[3]  = {12, 24, 48};
    const int    N2[3]  = {623808, 120000, 15552};
    const int    N3[3]  = {185193, 15625, 729};
    const size_t OF2[3] = {0, 3119040, 3719040};
    const size_t OF3[3] = {0, 925965, 1004090};

    const int O = Os[sc], s = Ss[sc], k = Ks[sc], n2 = N2[sc], n3 = N3[sc];
    int idx = bloc * 256 + threadIdx.x;
    if (idx >= 5 * n3) return;
    int c  = idx / n3;
    int r  = idx - c * n3;
    int ox = r % O;
    int t  = r / O;
    int oy = t % O;
    int oz = t / O;

    const float* p = B2 + OF2[sc] + (size_t)c * n2
                     + (size_t)(oz * s) * O * O + (size_t)oy * O + ox;
    float acc = 0.f;
    const int stride = 2 * O * O;
    for (int l = 0; l < k; ++l) acc += p[(size_t)l * stride];
    B3[OF3[sc] + idx] = acc;
}

// ---------------------------------------------------------------------------
// Fused LNCC reduce over all 3 scales; weight/mean folded per element.
// ---------------------------------------------------------------------------
__global__ __launch_bounds__(256) void reduce_all(
    const float* __restrict__ B3, float* __restrict__ partials)
{
    const int total = 185193 + 15625 + 729;   // 201547
    float local = 0.f;
    for (int i = blockIdx.x * 256 + threadIdx.x; i < total; i += gridDim.x * 256) {
        int r, n3; size_t off; float inv_numel, wdiv;
        if (i < 185193) {
            r = i; n3 = 185193; off = 0;
            inv_numel = 1.f / 1728.f;   wdiv = 0.1f / 185193.f;
        } else if (i < 200818) {
            r = i - 185193; n3 = 15625; off = 925965;
            inv_numel = 1.f / 13824.f;  wdiv = 0.3f / 15625.f;
        } else {
            r = i - 200818; n3 = 729; off = 1004090;
            inv_numel = 1.f / 110592.f; wdiv = 0.6f / 729.f;
        }
        const float* B = B3 + off;
        float i_s = B[r];
        float t_s = B[(size_t)n3 + r];
        float i2  = B[2 * (size_t)n3 + r];
        float t2  = B[3 * (size_t)n3 + r];
        float it  = B[4 * (size_t)n3 + r];
        float cross = it - i_s * t_s * inv_numel;
        float iv    = i2 - i_s * i_s * inv_numel;
        float tv    = t2 - t_s * t_s * inv_numel;
        local += wdiv * (cross * cross / (iv * tv + 1e-5f));
    }
    __shared__ float red[256];
    red[threadIdx.x] = local;
    __syncthreads();
    for (int o = 128; o > 0; o >>= 1) {
        if (threadIdx.x < o) red[threadIdx.x] += red[threadIdx.x + o];
        __syncthreads();
    }
    if (threadIdx.x == 0) partials[blockIdx.x] = red[0];
}

__global__ __launch_bounds__(256) void finalize_all(
    const float* __restrict__ partials, float* __restrict__ out)
{
    __shared__ float red[256];
    red[threadIdx.x] = partials[threadIdx.x];
    __syncthreads();
    for (int o = 128; o > 0; o >>= 1) {
        if (threadIdx.x < o) red[threadIdx.x] += red[threadIdx.x + o];
        __syncthreads();
    }
    if (threadIdx.x == 0) out[0] = 1.0f - red[0];   // sum of weights = 1.0
}

// ------------------- fallback kernels (small-ws paths) ---------------------
__global__ void pass1_one(const float* __restrict__ I, const float* __restrict__ T,
                          float* __restrict__ B1, int O, int s, int k, int c) {
    int idx = blockIdx.x * blockDim.x + threadIdx.x;
    int total = IMG * IMG * O;
    if (idx >= total) return;
    int ox = idx % O;
    int zy = idx / O;
    const float* pI = I + (size_t)zy * IMG + ox * s;
    const float* pT = T + (size_t)zy * IMG + ox * s;
    float acc = 0.f;
    for (int i = 0; i < k; ++i) {
        float v;
        if (c == 0)      v = pI[2 * i];
        else if (c == 1) v = pT[2 * i];
        else if (c == 2) { float a = pI[2 * i]; v = a * a; }
        else if (c == 3) { float bb = pT[2 * i]; v = bb * bb; }
        else             { v = pI[2 * i] * pT[2 * i]; }
        acc += v;
    }
    B1[idx] = acc;
}

__global__ void pass_y(const float* __restrict__ Bin, float* __restrict__ Bout,
                       int O, int s, int k, int nch, int n1, int n2) {
    int idx = blockIdx.x * blockDim.x + threadIdx.x;
    if (idx >= nch * n2) return;
    int c = idx / n2;
    int r = idx - c * n2;
    int ox = r % O;
    int t  = r / O;
    int oy = t % O;
    int z  = t / O;
    const float* p = Bin + (size_t)c * n1 + (size_t)z * IMG * O + (size_t)(oy * s) * O + ox;
    float acc = 0.f;
    int stride = 2 * O;
    for (int j = 0; j < k; ++j) acc += p[(size_t)j * stride];
    Bout[idx] = acc;
}

__global__ void pass_z(const float* __restrict__ Bin, float* __restrict__ Bout,
                       int O, int s, int k, int nch, int coff, int n2, int n3) {
    int idx = blockIdx.x * blockDim.x + threadIdx.x;
    if (idx >= nch * n3) return;
    int c = idx / n3;
    int r = idx - c * n3;
    int ox = r % O;
    int t  = r / O;
    int oy = t % O;
    int oz = t / O;
    const float* p = Bin + (size_t)c * n2 + (size_t)(oz * s) * O * O + (size_t)oy * O + ox;
    float acc = 0.f;
    int stride = 2 * O * O;
    for (int l = 0; l < k; ++l) acc += p[(size_t)l * stride];
    Bout[(size_t)(coff + c) * n3 + r] = acc;
}

// ---------------------------------------------------------------------------
extern "C" void kernel_launch(void* const* d_in, const int* in_sizes, int n_in,
                              void* d_out, int out_size, void* d_ws, size_t ws_size,
                              hipStream_t stream) {
    const float* I = (const float*)d_in[0];
    const float* T = (const float*)d_in[1];
    float* out = (float*)d_out;
    float* ws  = (float*)d_ws;

    const size_t szB1_all = 16773120;   // 5*(n1_0+n1_1+n1_2)
    const size_t szB2_all = 3796800;    // 5*(n2_0+n2_1+n2_2)
    const size_t szB3     = 1007735;    // 5*(n3_0+n3_1+n3_2)
    const size_t szB1_max = 10506240;   // 5*n1_0
    const size_t szB2_max = 3119040;    // 5*n2_0

    const size_t need_fused = (szB1_all + szB2_all + szB3 + 256) * sizeof(float);
    const size_t need_split = (szB1_max + szB2_max + szB3 + 256) * sizeof(float);

    const int   Ks[3]  = {12, 24, 48};
    const int   Ss[3]  = {3, 6, 12};
    const int   Os[3]  = {57, 25, 9};
    const int   N1[3]  = {2101248, 921600, 331776};
    const int   N2[3]  = {623808, 120000, 15552};
    const int   N3[3]  = {185193, 15625, 729};
    const size_t OF3[3] = {0, 925965, 1004090};

    if (ws_size >= need_fused) {
        float* B1 = ws;
        float* B2 = B1 + szB1_all;
        float* B3 = B2 + szB2_all;
        float* partials = B3 + szB3;
        pass1_lds<<<4608, 256, 0, stream>>>(I, T, B1, B1 + 10506240, B1 + 15114240);
        passY_all<<<14832, 256, 0, stream>>>(B1, B2);
        passZ_all<<<3939, 256, 0, stream>>>(B2, B3);
        reduce_all<<<256, 256, 0, stream>>>(B3, partials);
        finalize_all<<<1, 256, 0, stream>>>(partials, out);
    } else if (ws_size >= need_split) {
        float* B1 = ws;
        float* B2 = B1 + szB1_max;
        float* B3 = B2 + szB2_max;
        float* partials = B3 + szB3;
        for (int sc = 0; sc < 3; ++sc) {
            int k = Ks[sc], s = Ss[sc], O = Os[sc];
            int n1 = N1[sc], n2 = N2[sc], n3 = N3[sc];
            pass1_lds<<<4608, 256, 0, stream>>>(I, T,
                sc == 0 ? B1 : nullptr, sc == 1 ? B1 : nullptr, sc == 2 ? B1 : nullptr);
            pass_y<<<(5 * n2 + 255) / 256, 256, 0, stream>>>(B1, B2, O, s, k, 5, n1, n2);
            pass_z<<<(5 * n3 + 255) / 256, 256, 0, stream>>>(B2, B3 + OF3[sc], O, s, k, 5, 0, n2, n3);
        }
        reduce_all<<<256, 256, 0, stream>>>(B3, partials);
        finalize_all<<<1, 256, 0, stream>>>(partials, out);
    } else {
        // minimal-ws path: per scale, per channel
        float* B1 = ws;                      // n1_max
        float* B2 = B1 + 2101248;            // n2_max
        float* B3 = B2 + 623808;             // 5 * sum(n3)
        float* partials = B3 + szB3;
        for (int sc = 0; sc < 3; ++sc) {
            int k = Ks[sc], s = Ss[sc], O = Os[sc];
            int n1 = N1[sc], n2 = N2[sc], n3 = N3[sc];
            for (int c = 0; c < 5; ++c) {
                pass1_one<<<(n1 + 255) / 256, 256, 0, stream>>>(I, T, B1, O, s, k, c);
                pass_y<<<(n2 + 255) / 256, 256, 0, stream>>>(B1, B2, O, s, k, 1, n1, n2);
                pass_z<<<(n3 + 255) / 256, 256, 0, stream>>>(B2, B3 + OF3[sc], O, s, k, 1, c, n2, n3);
            }
        }
        reduce_all<<<256, 256, 0, stream>>>(B3, partials);
        finalize_all<<<1, 256, 0, stream>>>(partials, out);
    }
}

// Round 3
// 72.202 us; speedup vs baseline: 3.8345x; 1.6611x over previous
//
#include <hip/hip_runtime.h>

#define IMG 192
#define ROWP 196   // padded LDS row stride (floats), float4-aligned

// ---------------------------------------------------------------------------
// Pass 1 (x-direction): LDS-staged, coalesced, all 5 channels, 3 scales,
// compile-time K per section. Each block stages 8 contiguous rows of I and T.
// B layout per scale: [5][zy][ox], channel stride n1.
// ---------------------------------------------------------------------------
template<int O, int S, int K>
__device__ __forceinline__ void p1_compute(const float* __restrict__ lI,
                                           const float* __restrict__ lT,
                                           float* __restrict__ B,
                                           int row, int ox, int r0, int n1) {
    const float* a = &lI[row * ROWP + ox * S];
    const float* b = &lT[row * ROWP + ox * S];
    float sI = 0.f, sT = 0.f, sI2 = 0.f, sT2 = 0.f, sIT = 0.f;
#pragma unroll
    for (int i = 0; i < K; ++i) {
        float x = a[2 * i];
        float y = b[2 * i];
        sI += x; sT += y; sI2 += x * x; sT2 += y * y; sIT += x * y;
    }
    size_t o = (size_t)(r0 + row) * O + ox;
    B[o]                  = sI;
    B[(size_t)n1 + o]     = sT;
    B[2 * (size_t)n1 + o] = sI2;
    B[3 * (size_t)n1 + o] = sT2;
    B[4 * (size_t)n1 + o] = sIT;
}

__global__ __launch_bounds__(256) void pass1_lds(
    const float* __restrict__ I, const float* __restrict__ T,
    float* __restrict__ Bs0, float* __restrict__ Bs1, float* __restrict__ Bs2)
{
    __shared__ float lI[8 * ROWP];
    __shared__ float lT[8 * ROWP];
    const int tid = threadIdx.x;
    const int r0  = blockIdx.x * 8;                 // first row (zy index)

    const float4* I4 = (const float4*)(I + (size_t)r0 * IMG);
    const float4* T4 = (const float4*)(T + (size_t)r0 * IMG);
    float4* lI4 = (float4*)lI;
    float4* lT4 = (float4*)lT;
    for (int t = tid; t < 8 * (IMG / 4); t += 256) {   // 384 float4
        int row = t / 48, xi = t - row * 48;
        lI4[row * (ROWP / 4) + xi] = I4[t];
        lT4[row * (ROWP / 4) + xi] = T4[t];
    }
    __syncthreads();

    if (Bs0)
        for (int w = tid; w < 8 * 57; w += 256) {
            int row = w / 57, ox = w - row * 57;
            p1_compute<57, 3, 12>(lI, lT, Bs0, row, ox, r0, 2101248);
        }
    if (Bs1)
        for (int w = tid; w < 8 * 25; w += 256) {
            int row = w / 25, ox = w - row * 25;
            p1_compute<25, 6, 24>(lI, lT, Bs1, row, ox, r0, 921600);
        }
    if (Bs2)
        for (int w = tid; w < 8 * 9; w += 256) {
            int row = w / 9, ox = w - row * 9;
            p1_compute<9, 12, 48>(lI, lT, Bs2, row, ox, r0, 331776);
        }
}

// ---------------------------------------------------------------------------
// Pass 2 (y-direction), compile-time per-scale, one launch via block ranges.
// ---------------------------------------------------------------------------
template<int O, int S, int K, int N1, int N2>
__device__ __forceinline__ void passY_impl(const float* __restrict__ B1,
                                           float* __restrict__ B2, int idx) {
    if (idx >= 5 * N2) return;
    int c  = idx / N2;
    int r  = idx - c * N2;
    int ox = r % O;
    int t  = r / O;
    int oy = t % O;
    int z  = t / O;
    const float* p = B1 + (size_t)c * N1 + (size_t)z * IMG * O
                     + (size_t)(oy * S) * O + ox;
    float acc = 0.f;
#pragma unroll
    for (int j = 0; j < K; ++j) acc += p[j * 2 * O];
    B2[idx] = acc;
}

__global__ __launch_bounds__(256) void passY_all(
    const float* __restrict__ B1, float* __restrict__ B2)
{
    const int b = blockIdx.x;
    if (b < 12184)
        passY_impl<57, 3, 12, 2101248, 623808>(B1, B2, b * 256 + threadIdx.x);
    else if (b < 14528)
        passY_impl<25, 6, 24, 921600, 120000>(B1 + 10506240, B2 + 3119040,
                                              (b - 12184) * 256 + threadIdx.x);
    else
        passY_impl<9, 12, 48, 331776, 15552>(B1 + 15114240, B2 + 3719040,
                                             (b - 14528) * 256 + threadIdx.x);
}

// ---------------------------------------------------------------------------
// Pass 3 (z-direction) fused with LNCC + weighted partial reduction.
// Each thread: all 5 channel z-sums (unrolled), LNCC, wdiv folded.
// ---------------------------------------------------------------------------
template<int O, int S, int K, int N2, int N3>
__device__ __forceinline__ float passZ_lncc(const float* __restrict__ B2,
                                            int r, float inv_numel, float wdiv) {
    int ox = r % O;
    int t  = r / O;
    int oy = t % O;
    int oz = t / O;
    const float* p = B2 + (size_t)(oz * S) * O * O + (size_t)oy * O + ox;
    float s[5];
#pragma unroll
    for (int c = 0; c < 5; ++c) {
        float acc = 0.f;
        const float* q = p + (size_t)c * N2;
#pragma unroll
        for (int l = 0; l < K; ++l) acc += q[l * 2 * O * O];
        s[c] = acc;
    }
    float cross = s[4] - s[0] * s[1] * inv_numel;
    float iv    = s[2] - s[0] * s[0] * inv_numel;
    float tv    = s[3] - s[1] * s[1] * inv_numel;
    return wdiv * (cross * cross / (iv * tv + 1e-5f));
}

__global__ __launch_bounds__(256) void passZ_red(
    const float* __restrict__ B2, float* __restrict__ partials)
{
    const int b = blockIdx.x;
    float v = 0.f;
    if (b < 724) {
        int r = b * 256 + threadIdx.x;
        if (r < 185193)
            v = passZ_lncc<57, 3, 12, 623808, 185193>(B2, r, 1.f / 1728.f,
                                                      0.1f / 185193.f);
    } else if (b < 786) {
        int r = (b - 724) * 256 + threadIdx.x;
        if (r < 15625)
            v = passZ_lncc<25, 6, 24, 120000, 15625>(B2 + 3119040, r,
                                                     1.f / 13824.f, 0.3f / 15625.f);
    } else {
        int r = (b - 786) * 256 + threadIdx.x;
        if (r < 729)
            v = passZ_lncc<9, 12, 48, 15552, 729>(B2 + 3719040, r,
                                                  1.f / 110592.f, 0.6f / 729.f);
    }
    __shared__ float red[256];
    red[threadIdx.x] = v;
    __syncthreads();
    for (int o = 128; o > 0; o >>= 1) {
        if (threadIdx.x < o) red[threadIdx.x] += red[threadIdx.x + o];
        __syncthreads();
    }
    if (threadIdx.x == 0) partials[blockIdx.x] = red[0];
}

// ---------------------------------------------------------------------------
// finalize: out = 1 - sum(partials[0..n))     (sum of weights = 1.0)
// ---------------------------------------------------------------------------
__global__ __launch_bounds__(256) void finalize_n(
    const float* __restrict__ partials, int n, float* __restrict__ out)
{
    float v = 0.f;
    for (int i = threadIdx.x; i < n; i += 256) v += partials[i];
    __shared__ float red[256];
    red[threadIdx.x] = v;
    __syncthreads();
    for (int o = 128; o > 0; o >>= 1) {
        if (threadIdx.x < o) red[threadIdx.x] += red[threadIdx.x + o];
        __syncthreads();
    }
    if (threadIdx.x == 0) out[0] = 1.0f - red[0];
}

// ------------------- fallback kernels (small-ws paths) ---------------------
__global__ void pass1_one(const float* __restrict__ I, const float* __restrict__ T,
                          float* __restrict__ B1, int O, int s, int k, int c) {
    int idx = blockIdx.x * blockDim.x + threadIdx.x;
    if (idx >= IMG * IMG * O) return;
    int ox = idx % O;
    int zy = idx / O;
    const float* pI = I + (size_t)zy * IMG + ox * s;
    const float* pT = T + (size_t)zy * IMG + ox * s;
    float acc = 0.f;
    for (int i = 0; i < k; ++i) {
        float v;
        if (c == 0)      v = pI[2 * i];
        else if (c == 1) v = pT[2 * i];
        else if (c == 2) { float a = pI[2 * i]; v = a * a; }
        else if (c == 3) { float bb = pT[2 * i]; v = bb * bb; }
        else             { v = pI[2 * i] * pT[2 * i]; }
        acc += v;
    }
    B1[idx] = acc;
}

__global__ void pass_y(const float* __restrict__ Bin, float* __restrict__ Bout,
                       int O, int s, int k, int nch, int n1, int n2) {
    int idx = blockIdx.x * blockDim.x + threadIdx.x;
    if (idx >= nch * n2) return;
    int c = idx / n2;
    int r = idx - c * n2;
    int ox = r % O;
    int t  = r / O;
    int oy = t % O;
    int z  = t / O;
    const float* p = Bin + (size_t)c * n1 + (size_t)z * IMG * O + (size_t)(oy * s) * O + ox;
    float acc = 0.f;
    for (int j = 0; j < k; ++j) acc += p[(size_t)j * 2 * O];
    Bout[idx] = acc;
}

__global__ void pass_z(const float* __restrict__ Bin, float* __restrict__ Bout,
                       int O, int s, int k, int nch, int n2, int n3) {
    int idx = blockIdx.x * blockDim.x + threadIdx.x;
    if (idx >= nch * n3) return;
    int c = idx / n3;
    int r = idx - c * n3;
    int ox = r % O;
    int t  = r / O;
    int oy = t % O;
    int oz = t / O;
    const float* p = Bin + (size_t)c * n2 + (size_t)(oz * s) * O * O + (size_t)oy * O + ox;
    float acc = 0.f;
    for (int l = 0; l < k; ++l) acc += p[(size_t)l * 2 * O * O];
    Bout[(size_t)c * n3 + r] = acc;
}

__global__ void reduce_one(const float* __restrict__ B3, int n3, float inv_numel,
                           float wdiv, float* __restrict__ partials) {
    float local = 0.f;
    for (int i = blockIdx.x * 256 + threadIdx.x; i < n3; i += gridDim.x * 256) {
        float i_s = B3[i];
        float t_s = B3[(size_t)n3 + i];
        float i2  = B3[2 * (size_t)n3 + i];
        float t2  = B3[3 * (size_t)n3 + i];
        float it  = B3[4 * (size_t)n3 + i];
        float cross = it - i_s * t_s * inv_numel;
        float iv    = i2 - i_s * i_s * inv_numel;
        float tv    = t2 - t_s * t_s * inv_numel;
        local += wdiv * (cross * cross / (iv * tv + 1e-5f));
    }
    __shared__ float red[256];
    red[threadIdx.x] = local;
    __syncthreads();
    for (int o = 128; o > 0; o >>= 1) {
        if (threadIdx.x < o) red[threadIdx.x] += red[threadIdx.x + o];
        __syncthreads();
    }
    if (threadIdx.x == 0) partials[blockIdx.x] += red[0];   // accumulate scales
}

__global__ void zero_buf(float* __restrict__ p, int n) {
    int i = blockIdx.x * 256 + threadIdx.x;
    if (i < n) p[i] = 0.f;
}

// ---------------------------------------------------------------------------
extern "C" void kernel_launch(void* const* d_in, const int* in_sizes, int n_in,
                              void* d_out, int out_size, void* d_ws, size_t ws_size,
                              hipStream_t stream) {
    const float* I = (const float*)d_in[0];
    const float* T = (const float*)d_in[1];
    float* out = (float*)d_out;
    float* ws  = (float*)d_ws;

    const size_t szB1_all = 16773120;   // 5*(n1_0+n1_1+n1_2)
    const size_t szB2_all = 3796800;    // 5*(n2_0+n2_1+n2_2)

    const size_t need_fused = (szB1_all + szB2_all + 1024) * sizeof(float);

    if (ws_size >= need_fused) {
        float* B1 = ws;
        float* B2 = B1 + szB1_all;
        float* partials = B2 + szB2_all;
        pass1_lds<<<4608, 256, 0, stream>>>(I, T, B1, B1 + 10506240, B1 + 15114240);
        passY_all<<<14832, 256, 0, stream>>>(B1, B2);
        passZ_red<<<789, 256, 0, stream>>>(B2, partials);
        finalize_n<<<1, 256, 0, stream>>>(partials, 789, out);
    } else {
        // minimal-ws path: per scale, per channel pipelines
        const int   Ks[3] = {12, 24, 48};
        const int   Ss[3] = {3, 6, 12};
        const int   Os[3] = {57, 25, 9};
        const int   N1[3] = {2101248, 921600, 331776};
        const int   N2[3] = {623808, 120000, 15552};
        const int   N3[3] = {185193, 15625, 729};
        const float Wt[3] = {0.1f, 0.3f, 0.6f};

        float* B1 = ws;                 // n1_max = 2101248
        float* B2 = B1 + 2101248;       // n2_max = 623808
        float* B3 = B2 + 623808;        // 5 * n3_max = 925965
        float* partials = B3 + 925965;  // 256

        zero_buf<<<1, 256, 0, stream>>>(partials, 256);
        for (int sc = 0; sc < 3; ++sc) {
            int k = Ks[sc], s = Ss[sc], O = Os[sc];
            int n1 = N1[sc], n2 = N2[sc], n3 = N3[sc];
            for (int c = 0; c < 5; ++c) {
                pass1_one<<<(n1 + 255) / 256, 256, 0, stream>>>(I, T, B1, O, s, k, c);
                pass_y<<<(n2 + 255) / 256, 256, 0, stream>>>(B1, B2, O, s, k, 1, n1, n2);
                pass_z<<<(n3 + 255) / 256, 256, 0, stream>>>(B2, B3 + (size_t)c * n3, O, s, k, 1, n2, n3);
            }
            int nblk = (n3 + 255) / 256; if (nblk > 256) nblk = 256;
            reduce_one<<<nblk, 256, 0, stream>>>(B3, n3, 1.f / ((float)k * k * k),
                                                 Wt[sc] / (float)n3, partials);
        }
        finalize_n<<<1, 256, 0, stream>>>(partials, 256, out);
    }
}